// Round 1
// baseline (229.865 us; speedup 1.0000x reference)
//
#include <hip/hip_runtime.h>

// EDeeperGCN: out[e] = relu(cat(x[src],x[dst]) @ W1 + b1) @ W2 + b2
// Restructured: A = x@W1[:H] + b1, B = x@W1[H:]  (per node, in d_ws)
//               out[e] = relu(A[src[e]] + B[dst[e]]) @ W2 + b2

#define HID  128
#define TWOH 256
#define OUTD 10
#define NPB  16   // nodes per block, kernel 1
#define EPT  4    // edges per thread, kernel 2

// ---------------- Kernel 1: per-node precompute AB = [x@W1_top + b1 | x@W1_bot] ----------------
__global__ __launch_bounds__(256) void precompute_AB(
    const float* __restrict__ x,    // [N, 128]
    const float* __restrict__ W1,   // [256, 128]
    const float* __restrict__ b1,   // [128]
    float* __restrict__ AB,         // [N, 256]
    int n_nodes)
{
    const int t = threadIdx.x;                 // 0..255: output column of AB
    const int node0 = blockIdx.x * NPB;
    // column t<128 -> A half: W1 rows 0..127, col t
    // column t>=128 -> B half: W1 rows 128..255, col t-128
    const float* wcol = (t < HID) ? (W1 + t) : (W1 + HID * HID + (t - HID));

    float acc[NPB];
#pragma unroll
    for (int n = 0; n < NPB; ++n) acc[n] = 0.f;

    const float* xb = x + (long)node0 * HID;   // 10000 % 16 == 0: no OOB reads
    for (int k = 0; k < HID; ++k) {
        const float w = wcol[(long)k * HID];   // coalesced across lanes
#pragma unroll
        for (int n = 0; n < NPB; ++n)
            acc[n] = fmaf(xb[n * HID + k], w, acc[n]);   // x read is lane-uniform -> s_load
    }

    const float bias = (t < HID) ? b1[t] : 0.f;
#pragma unroll
    for (int n = 0; n < NPB; ++n) {
        const int node = node0 + n;
        if (node < n_nodes) AB[(long)node * TWOH + t] = acc[n] + bias;
    }
}

// ---------------- Kernel 2: per-edge gather + relu + [128x10] GEMM ----------------
__global__ __launch_bounds__(256) void edge_mlp(
    const float* __restrict__ AB,   // [N, 256]
    const int* __restrict__ ei,     // [2, E] (src row then dst row)
    const float* __restrict__ W2,   // [128, 10]
    const float* __restrict__ b2,   // [10]
    float* __restrict__ out,        // [E, 10]
    int n_edges)
{
    __shared__ float w2s[HID][12];  // 12-float rows: 48B, keeps float4 reads 16B-aligned
    __shared__ float b2s[OUTD];

    const int t = threadIdx.x;
    for (int i = t; i < HID * OUTD; i += 256) w2s[i / OUTD][i % OUTD] = W2[i];
    if (t < OUTD) b2s[t] = b2[t];
    __syncthreads();

    const long base = (long)blockIdx.x * (256 * EPT) + t;  // strided: coalesced ei loads/out stores

    int srcn[EPT], dstn[EPT];
    bool valid[EPT];
#pragma unroll
    for (int i = 0; i < EPT; ++i) {
        const long e = base + (long)i * 256;
        valid[i] = (e < n_edges);
        const long ec = valid[i] ? e : 0;
        srcn[i] = ei[ec];
        dstn[i] = ei[(long)n_edges + ec];
    }

    float bj[OUTD];
#pragma unroll
    for (int j = 0; j < OUTD; ++j) bj[j] = b2s[j];

    float acc[EPT][OUTD];
#pragma unroll
    for (int i = 0; i < EPT; ++i)
#pragma unroll
        for (int j = 0; j < OUTD; ++j) acc[i][j] = bj[j];

    for (int kk = 0; kk < HID / 4; ++kk) {
        float4 h4[EPT];
#pragma unroll
        for (int i = 0; i < EPT; ++i) {
            const float4 a4 = *(const float4*)(AB + (long)srcn[i] * TWOH + kk * 4);
            const float4 c4 = *(const float4*)(AB + (long)dstn[i] * TWOH + HID + kk * 4);
            h4[i].x = fmaxf(a4.x + c4.x, 0.f);
            h4[i].y = fmaxf(a4.y + c4.y, 0.f);
            h4[i].z = fmaxf(a4.z + c4.z, 0.f);
            h4[i].w = fmaxf(a4.w + c4.w, 0.f);
        }
#pragma unroll
        for (int d = 0; d < 4; ++d) {
            const int k = kk * 4 + d;
            const float4 w0 = *(const float4*)&w2s[k][0];   // LDS broadcast, conflict-free
            const float4 w1 = *(const float4*)&w2s[k][4];
            const float2 wv = *(const float2*)&w2s[k][8];
#pragma unroll
            for (int i = 0; i < EPT; ++i) {
                const float h = (d == 0) ? h4[i].x : (d == 1) ? h4[i].y
                              : (d == 2) ? h4[i].z : h4[i].w;
                acc[i][0] = fmaf(h, w0.x, acc[i][0]);
                acc[i][1] = fmaf(h, w0.y, acc[i][1]);
                acc[i][2] = fmaf(h, w0.z, acc[i][2]);
                acc[i][3] = fmaf(h, w0.w, acc[i][3]);
                acc[i][4] = fmaf(h, w1.x, acc[i][4]);
                acc[i][5] = fmaf(h, w1.y, acc[i][5]);
                acc[i][6] = fmaf(h, w1.z, acc[i][6]);
                acc[i][7] = fmaf(h, w1.w, acc[i][7]);
                acc[i][8] = fmaf(h, wv.x, acc[i][8]);
                acc[i][9] = fmaf(h, wv.y, acc[i][9]);
            }
        }
    }

#pragma unroll
    for (int i = 0; i < EPT; ++i) {
        if (!valid[i]) continue;
        const long e = base + (long)i * 256;
        float* o = out + e * OUTD;                 // 40B rows, 8B aligned
        *(float2*)(o + 0) = make_float2(acc[i][0], acc[i][1]);
        *(float2*)(o + 2) = make_float2(acc[i][2], acc[i][3]);
        *(float2*)(o + 4) = make_float2(acc[i][4], acc[i][5]);
        *(float2*)(o + 6) = make_float2(acc[i][6], acc[i][7]);
        *(float2*)(o + 8) = make_float2(acc[i][8], acc[i][9]);
    }
}

extern "C" void kernel_launch(void* const* d_in, const int* in_sizes, int n_in,
                              void* d_out, int out_size, void* d_ws, size_t ws_size,
                              hipStream_t stream) {
    const float* x  = (const float*)d_in[0];
    const int*   ei = (const int*)d_in[1];
    const float* W1 = (const float*)d_in[2];
    const float* b1 = (const float*)d_in[3];
    const float* W2 = (const float*)d_in[4];
    const float* b2 = (const float*)d_in[5];
    float* out = (float*)d_out;

    const int n_nodes = in_sizes[0] / HID;          // 10000
    const int n_edges = in_sizes[1] / 2;            // 640000

    float* AB = (float*)d_ws;                       // [n_nodes, 256] fp32 = 10.24 MB

    precompute_AB<<<(n_nodes + NPB - 1) / NPB, 256, 0, stream>>>(x, W1, b1, AB, n_nodes);

    const int edges_per_block = 256 * EPT;
    edge_mlp<<<(n_edges + edges_per_block - 1) / edges_per_block, 256, 0, stream>>>(
        AB, ei, W2, b2, out, n_edges);
}

// Round 2
// 119.708 us; speedup vs baseline: 1.9202x; 1.9202x over previous
//
#include <hip/hip_runtime.h>

// EDeeperGCN: out[e] = relu(cat(x[src],x[dst]) @ W1 + b1) @ W2 + b2
// Restructured: AB[n] = [x[n]@W1_top + b1 | x[n]@W1_bot]  (fp16, in d_ws)
//               out[e] = relu(A[src[e]] + B[dst[e]]) @ W2 + b2   (dot2 f16->f32)

typedef __fp16 h2 __attribute__((ext_vector_type(2)));
typedef __fp16 h8 __attribute__((ext_vector_type(8)));

#define HID  128
#define TWOH 256
#define OUTD 10
#define NPB  16   // nodes per block, kernel 1
#define EPT  2    // edges per thread, kernel 2

// ---------------- Kernel 1: AB = [x@W1_top + b1 | x@W1_bot], fp16 output ----------------
__global__ __launch_bounds__(256) void precompute_AB(
    const float* __restrict__ x,    // [N, 128]
    const float* __restrict__ W1,   // [256, 128]
    const float* __restrict__ b1,   // [128]
    __fp16* __restrict__ AB,        // [N, 256]
    int n_nodes)
{
    __shared__ float xs[NPB][HID];          // 8 KB x-tile
    const int t = threadIdx.x;              // 0..255: output column of AB
    const int node0 = blockIdx.x * NPB;     // 10000 % 16 == 0: tile always full

    const float4* xg = (const float4*)(x + (long)node0 * HID);
    float4* xs4 = (float4*)xs;
#pragma unroll
    for (int i = 0; i < (NPB * HID / 4) / 256; ++i)     // 2 iters, coalesced
        xs4[t + i * 256] = xg[t + i * 256];
    __syncthreads();

    const float* wcol = (t < HID) ? (W1 + t) : (W1 + HID * HID + (t - HID));

    float acc[NPB];
#pragma unroll
    for (int n = 0; n < NPB; ++n) acc[n] = 0.f;

    for (int k = 0; k < HID; ++k) {
        const float w = wcol[(long)k * HID];   // coalesced across lanes
#pragma unroll
        for (int n = 0; n < NPB; ++n)
            acc[n] = fmaf(xs[n][k], w, acc[n]);   // lane-uniform -> LDS broadcast
    }

    const float bias = (t < HID) ? b1[t] : 0.f;
#pragma unroll
    for (int n = 0; n < NPB; ++n) {
        const int node = node0 + n;
        if (node < n_nodes) AB[(long)node * TWOH + t] = (__fp16)(acc[n] + bias);
    }
}

// ---------------- Kernel 2: per-edge gather(fp16) + relu + [128x10] dot2 GEMM ----------------
__global__ __launch_bounds__(256) void edge_mlp(
    const __fp16* __restrict__ AB,  // [N, 256]
    const int* __restrict__ ei,     // [2, E]
    const float* __restrict__ W2,   // [128, 10]
    const float* __restrict__ b2,   // [10]
    float* __restrict__ out,        // [E, 10]
    int n_edges)
{
    __shared__ h2 w2s[HID / 2][12];   // [64][12]: 48B rows keep b128 reads aligned
    const int t = threadIdx.x;
    for (int i = t; i < (HID / 2) * OUTD; i += 256) {
        const int kp = i / OUTD, j = i % OUTD;
        h2 v;
        v.x = (__fp16)W2[(2 * kp) * OUTD + j];
        v.y = (__fp16)W2[(2 * kp + 1) * OUTD + j];
        w2s[kp][j] = v;
    }
    __syncthreads();

    const long base = (long)blockIdx.x * (256 * EPT) + t;  // coalesced ei / out
    const long e0 = base, e1 = base + 256;
    const bool v0 = e0 < n_edges, v1 = e1 < n_edges;
    const long c0 = v0 ? e0 : 0, c1 = v1 ? e1 : 0;
    const int sn0 = ei[c0], dn0 = ei[(long)n_edges + c0];
    const int sn1 = ei[c1], dn1 = ei[(long)n_edges + c1];

    const h8* __restrict__ A0 = (const h8*)(AB + (long)sn0 * TWOH);        // 16B chunks
    const h8* __restrict__ B0 = (const h8*)(AB + (long)dn0 * TWOH + HID);
    const h8* __restrict__ A1 = (const h8*)(AB + (long)sn1 * TWOH);
    const h8* __restrict__ B1 = (const h8*)(AB + (long)dn1 * TWOH + HID);

    float acc0[OUTD], acc1[OUTD];
#pragma unroll
    for (int j = 0; j < OUTD; ++j) { acc0[j] = b2[j]; acc1[j] = b2[j]; }  // uniform -> s_load

    // double-buffered gather: prefetch chunk kk+1 while computing chunk kk
    h8 a0c = A0[0], b0c = B0[0], a1c = A1[0], b1c = B1[0];

    for (int kk = 0; kk < 16; ++kk) {
        const int nk = (kk + 1) & 15;          // branch-free; last prefetch is harmless dup
        h8 a0n = A0[nk], b0n = B0[nk], a1n = A1[nk], b1n = B1[nk];

        const h8 z = {0, 0, 0, 0, 0, 0, 0, 0};
        h8 s0 = a0c + b0c;                     // v_pk_add_f16
        s0 = __builtin_elementwise_max(s0, z); // v_pk_max_f16 (relu)
        h8 s1 = a1c + b1c;
        s1 = __builtin_elementwise_max(s1, z);

#pragma unroll
        for (int p = 0; p < 4; ++p) {
            const int kp = 4 * kk + p;
            const uint4 wa = *(const uint4*)&w2s[kp][0];   // LDS broadcast b128
            const uint4 wb = *(const uint4*)&w2s[kp][4];
            const uint2 wc = *(const uint2*)&w2s[kp][8];
            const unsigned wv[10] = {wa.x, wa.y, wa.z, wa.w,
                                     wb.x, wb.y, wb.z, wb.w,
                                     wc.x, wc.y};
            h2 hp0, hp1;
            hp0.x = s0[2 * p]; hp0.y = s0[2 * p + 1];
            hp1.x = s1[2 * p]; hp1.y = s1[2 * p + 1];
#pragma unroll
            for (int j = 0; j < OUTD; ++j) {
                const h2 w = __builtin_bit_cast(h2, wv[j]);
                acc0[j] = __builtin_amdgcn_fdot2(hp0, w, acc0[j], false);
                acc1[j] = __builtin_amdgcn_fdot2(hp1, w, acc1[j], false);
            }
        }
        a0c = a0n; b0c = b0n; a1c = a1n; b1c = b1n;
    }

    if (v0) {
        float* o = out + e0 * OUTD;
        *(float2*)(o + 0) = make_float2(acc0[0], acc0[1]);
        *(float2*)(o + 2) = make_float2(acc0[2], acc0[3]);
        *(float2*)(o + 4) = make_float2(acc0[4], acc0[5]);
        *(float2*)(o + 6) = make_float2(acc0[6], acc0[7]);
        *(float2*)(o + 8) = make_float2(acc0[8], acc0[9]);
    }
    if (v1) {
        float* o = out + e1 * OUTD;
        *(float2*)(o + 0) = make_float2(acc1[0], acc1[1]);
        *(float2*)(o + 2) = make_float2(acc1[2], acc1[3]);
        *(float2*)(o + 4) = make_float2(acc1[4], acc1[5]);
        *(float2*)(o + 6) = make_float2(acc1[6], acc1[7]);
        *(float2*)(o + 8) = make_float2(acc1[8], acc1[9]);
    }
}

extern "C" void kernel_launch(void* const* d_in, const int* in_sizes, int n_in,
                              void* d_out, int out_size, void* d_ws, size_t ws_size,
                              hipStream_t stream) {
    const float* x  = (const float*)d_in[0];
    const int*   ei = (const int*)d_in[1];
    const float* W1 = (const float*)d_in[2];
    const float* b1 = (const float*)d_in[3];
    const float* W2 = (const float*)d_in[4];
    const float* b2 = (const float*)d_in[5];
    float* out = (float*)d_out;

    const int n_nodes = in_sizes[0] / HID;          // 10000
    const int n_edges = in_sizes[1] / 2;            // 640000

    __fp16* AB = (__fp16*)d_ws;                     // [n_nodes, 256] fp16 = 5.12 MB

    precompute_AB<<<(n_nodes + NPB - 1) / NPB, 256, 0, stream>>>(x, W1, b1, AB, n_nodes);

    const int edges_per_block = 256 * EPT;
    edge_mlp<<<(n_edges + edges_per_block - 1) / edges_per_block, 256, 0, stream>>>(
        AB, ei, W2, b2, out, n_edges);
}

// Round 3
// 61.882 us; speedup vs baseline: 3.7146x; 1.9345x over previous
//
#include <hip/hip_runtime.h>

// EDeeperGCN: out[e] = relu(cat(x[src],x[dst]) @ W1 + b1) @ W2 + b2
// Restructured: AB[n] = [x[n]@W1_top + b1 | x[n]@W1_bot]  (fp16, in d_ws)
//               out[e] = relu(A[src[e]] + B[dst[e]]) @ W2 + b2   (dot2 f16->f32)
// Kernel 2 uses 4 lanes per edge: each gather instruction = one aligned 64B
// L2 line per edge (4x fewer L2 requests than 16B/lane random gathers).

typedef __fp16 h2 __attribute__((ext_vector_type(2)));
typedef __fp16 h8 __attribute__((ext_vector_type(8)));

#define HID  128
#define TWOH 256
#define OUTD 10
#define NPB  16   // nodes per block, kernel 1
#define EPG  4    // edges per 4-lane group, kernel 2

// ---------------- Kernel 1: AB = [x@W1_top + b1 | x@W1_bot], fp16 output ----------------
__global__ __launch_bounds__(256) void precompute_AB(
    const float* __restrict__ x,    // [N, 128]
    const float* __restrict__ W1,   // [256, 128]
    const float* __restrict__ b1,   // [128]
    __fp16* __restrict__ AB,        // [N, 256]
    int n_nodes)
{
    __shared__ float xs[NPB][HID];          // 8 KB x-tile
    const int t = threadIdx.x;              // 0..255: output column of AB
    const int node0 = blockIdx.x * NPB;     // 10000 % 16 == 0: tile always full

    const float4* xg = (const float4*)(x + (long)node0 * HID);
    float4* xs4 = (float4*)xs;
#pragma unroll
    for (int i = 0; i < (NPB * HID / 4) / 256; ++i)     // 2 iters, coalesced
        xs4[t + i * 256] = xg[t + i * 256];
    __syncthreads();

    const float* wcol = (t < HID) ? (W1 + t) : (W1 + HID * HID + (t - HID));

    float acc[NPB];
#pragma unroll
    for (int n = 0; n < NPB; ++n) acc[n] = 0.f;

    for (int k = 0; k < HID; ++k) {
        const float w = wcol[(long)k * HID];   // coalesced across lanes
#pragma unroll
        for (int n = 0; n < NPB; ++n)
            acc[n] = fmaf(xs[n][k], w, acc[n]);   // lane-uniform -> LDS broadcast
    }

    const float bias = (t < HID) ? b1[t] : 0.f;
#pragma unroll
    for (int n = 0; n < NPB; ++n) {
        const int node = node0 + n;
        if (node < n_nodes) AB[(long)node * TWOH + t] = (__fp16)(acc[n] + bias);
    }
}

// ---------------- Kernel 2: 4 lanes per edge, line-perfect gather + dot2 GEMM ----------------
__global__ __launch_bounds__(256) void edge_mlp(
    const __fp16* __restrict__ AB,  // [N, 256]
    const int* __restrict__ ei,     // [2, E]
    const float* __restrict__ W2,   // [128, 10]
    const float* __restrict__ b2,   // [10]
    float* __restrict__ out,        // [E, 10]
    int n_edges)
{
    __shared__ h2 w2s[HID / 2][12];   // [64][12]: 48B rows, b128-aligned
    const int t = threadIdx.x;
    for (int i = t; i < (HID / 2) * OUTD; i += 256) {
        const int kp = i / OUTD, j = i % OUTD;
        h2 v;
        v.x = (__fp16)W2[(2 * kp) * OUTD + j];
        v.y = (__fp16)W2[(2 * kp + 1) * OUTD + j];
        w2s[kp][j] = v;
    }
    __syncthreads();

    const int l = t & 3;          // lane within 4-lane group
    const int g = t >> 2;         // group 0..63 within block
    const long blockbase = (long)blockIdx.x * (64 * EPG);

    // per-lane slice of b2 for the final store
    const float2 bl    = *(const float2*)(b2 + 2 * l);
    const float2 btail = *(const float2*)(b2 + 8);

    // hoist all EPG index pairs (4 lanes of a group read the same addr -> broadcast)
    int sn[EPG], dn[EPG];
    bool valid[EPG];
#pragma unroll
    for (int i = 0; i < EPG; ++i) {
        const long e = blockbase + (long)i * 64 + g;
        valid[i] = (e < n_edges);
        const long ec = valid[i] ? e : 0;
        sn[i] = ei[ec];
        dn[i] = ei[(long)n_edges + ec];
    }

#pragma unroll
    for (int i = 0; i < EPG; ++i) {
        if (!valid[i]) continue;
        const long e = blockbase + (long)i * 64 + g;

        const h8* Arow = (const h8*)(AB + (long)sn[i] * TWOH);        // 16 chunks
        const h8* Brow = (const h8*)(AB + (long)dn[i] * TWOH + HID);  // 16 chunks

        // lane's chunks: c = 4*ii + l  -> instr ii touches one 64B line per edge
        const h8 a0 = Arow[l],      b0 = Brow[l];
        const h8 a1 = Arow[4 + l],  b1v = Brow[4 + l];
        const h8 a2 = Arow[8 + l],  b2v = Brow[8 + l];
        const h8 a3 = Arow[12 + l], b3v = Brow[12 + l];

        float acc[OUTD];
#pragma unroll
        for (int j = 0; j < OUTD; ++j) acc[j] = 0.f;

        const h8 z = {0, 0, 0, 0, 0, 0, 0, 0};
        h8 sچ[4];
        sچ[0] = __builtin_elementwise_max(a0 + b0, z);
        sچ[1] = __builtin_elementwise_max(a1 + b1v, z);
        sچ[2] = __builtin_elementwise_max(a2 + b2v, z);
        sچ[3] = __builtin_elementwise_max(a3 + b3v, z);

#pragma unroll
        for (int ii = 0; ii < 4; ++ii) {
            const h8 s = sچ[ii];
#pragma unroll
            for (int p = 0; p < 4; ++p) {
                const int kp = 16 * ii + 4 * l + p;     // lane stride 4 rows -> 2-way bank, free
                const uint4 wa = *(const uint4*)&w2s[kp][0];
                const uint4 wb = *(const uint4*)&w2s[kp][4];
                const uint2 wc = *(const uint2*)&w2s[kp][8];
                const unsigned wv[10] = {wa.x, wa.y, wa.z, wa.w,
                                         wb.x, wb.y, wb.z, wb.w,
                                         wc.x, wc.y};
                h2 hp;
                hp.x = s[2 * p]; hp.y = s[2 * p + 1];
#pragma unroll
                for (int j = 0; j < OUTD; ++j) {
                    const h2 w = __builtin_bit_cast(h2, wv[j]);
                    acc[j] = __builtin_amdgcn_fdot2(hp, w, acc[j], false);
                }
            }
        }

        // butterfly reduce across the 4-lane group (all lanes end with full sums)
#pragma unroll
        for (int j = 0; j < OUTD; ++j) {
            acc[j] += __shfl_xor(acc[j], 1);
            acc[j] += __shfl_xor(acc[j], 2);
        }

        float* o = out + e * OUTD;                     // 40B rows
        *(float2*)(o + 2 * l) = make_float2(acc[2 * l] + bl.x, acc[2 * l + 1] + bl.y);
        if (l == 0)
            *(float2*)(o + 8) = make_float2(acc[8] + btail.x, acc[9] + btail.y);
    }
}

extern "C" void kernel_launch(void* const* d_in, const int* in_sizes, int n_in,
                              void* d_out, int out_size, void* d_ws, size_t ws_size,
                              hipStream_t stream) {
    const float* x  = (const float*)d_in[0];
    const int*   ei = (const int*)d_in[1];
    const float* W1 = (const float*)d_in[2];
    const float* b1 = (const float*)d_in[3];
    const float* W2 = (const float*)d_in[4];
    const float* b2 = (const float*)d_in[5];
    float* out = (float*)d_out;

    const int n_nodes = in_sizes[0] / HID;          // 10000
    const int n_edges = in_sizes[1] / 2;            // 640000

    __fp16* AB = (__fp16*)d_ws;                     // [n_nodes, 256] fp16 = 5.12 MB

    precompute_AB<<<(n_nodes + NPB - 1) / NPB, 256, 0, stream>>>(x, W1, b1, AB, n_nodes);

    const int edges_per_block = 64 * EPG;           // 256 edges/block -> 2500 blocks
    edge_mlp<<<(n_edges + edges_per_block - 1) / edges_per_block, 256, 0, stream>>>(
        AB, ei, W2, b2, out, n_edges);
}